// Round 2
// baseline (352.589 us; speedup 1.0000x reference)
//
#include <hip/hip_runtime.h>
#include <hip/hip_bf16.h>

// Problem: B=32, S=512, D_MODEL=256, H=16, D_K=D_V=16
// inputs: Q,K,V [B,S,256] f32; mask [B,S] f32; W_* [256,256] f32 (out,in); b_* [256] f32
// out: [B,S,256] f32

#define PROJ_ELEMS (32 * 16 * 512 * 16) // 4,194,304 floats per projected tensor

// ---------------------------------------------------------------------------
// Projection GEMM: y[row][c] = sum_d X[row][d] * W[c][d] + b[c]
// rows = B*S = 16384, cols = 256, K = 256.
// Tile 128x128, BK=32, 256 threads, 8x8 micro-tile per thread.
// Output written in [B, H, S, D] layout into workspace.
// ---------------------------------------------------------------------------
__global__ __launch_bounds__(256, 4) void proj_kernel(
    const float* __restrict__ Qx, const float* __restrict__ Kx, const float* __restrict__ Vx,
    const float* __restrict__ WQ, const float* __restrict__ bQ,
    const float* __restrict__ WK, const float* __restrict__ bK,
    const float* __restrict__ WV, const float* __restrict__ bV,
    float* __restrict__ qp, float* __restrict__ kp, float* __restrict__ vp)
{
    const int proj = blockIdx.z;
    const float* __restrict__ X  = (proj == 0) ? Qx : (proj == 1) ? Kx : Vx;
    const float* __restrict__ W  = (proj == 0) ? WQ : (proj == 1) ? WK : WV;
    const float* __restrict__ bb = (proj == 0) ? bQ : (proj == 1) ? bK : bV;
    float* __restrict__ outp     = (proj == 0) ? qp : (proj == 1) ? kp : vp;

    const int row0 = blockIdx.x * 128;
    const int col0 = blockIdx.y * 128;
    const int t  = threadIdx.x;
    const int tc = t & 15;   // col group (8 cols each)
    const int tr = t >> 4;   // row group (8 rows each)

    // k-major (transposed) staging; stride 132 keeps float4 alignment and
    // spreads the k-write across banks (4*k + r) % 32.
    __shared__ float xs[32][132];
    __shared__ float wsh[32][132];

    float acc[8][8];
#pragma unroll
    for (int i = 0; i < 8; i++)
#pragma unroll
        for (int j = 0; j < 8; j++) acc[i][j] = 0.f;

    for (int k0 = 0; k0 < 256; k0 += 32) {
        __syncthreads();
#pragma unroll
        for (int i = 0; i < 4; i++) {
            int f = t + i * 256;        // 1024 float4s: 128 rows x 8 quads
            int r = f >> 3, kq = f & 7;
            float4 xv = *(const float4*)&X[(row0 + r) * 256 + k0 + kq * 4];
            float4 wv = *(const float4*)&W[(col0 + r) * 256 + k0 + kq * 4];
            xs[kq * 4 + 0][r] = xv.x; xs[kq * 4 + 1][r] = xv.y;
            xs[kq * 4 + 2][r] = xv.z; xs[kq * 4 + 3][r] = xv.w;
            wsh[kq * 4 + 0][r] = wv.x; wsh[kq * 4 + 1][r] = wv.y;
            wsh[kq * 4 + 2][r] = wv.z; wsh[kq * 4 + 3][r] = wv.w;
        }
        __syncthreads();
#pragma unroll 8
        for (int kk = 0; kk < 32; kk++) {
            float4 xa = *(const float4*)&xs[kk][tr * 8];
            float4 xb = *(const float4*)&xs[kk][tr * 8 + 4];
            float4 wa = *(const float4*)&wsh[kk][tc * 8];
            float4 wb = *(const float4*)&wsh[kk][tc * 8 + 4];
            float xr[8] = {xa.x, xa.y, xa.z, xa.w, xb.x, xb.y, xb.z, xb.w};
            float wr[8] = {wa.x, wa.y, wa.z, wa.w, wb.x, wb.y, wb.z, wb.w};
#pragma unroll
            for (int i = 0; i < 8; i++)
#pragma unroll
                for (int j = 0; j < 8; j++) acc[i][j] += xr[i] * wr[j];
        }
    }

    // epilogue: +bias, scatter to [B,H,S,D] (thread's 8 cols live in ONE head)
    const int c0 = col0 + tc * 8;
    const int h  = c0 >> 4;
    const int d0 = c0 & 15; // 0 or 8
    float bl[8];
#pragma unroll
    for (int j = 0; j < 8; j++) bl[j] = bb[c0 + j];
#pragma unroll
    for (int i = 0; i < 8; i++) {
        int row = row0 + tr * 8 + i;
        int b = row >> 9, s = row & 511;
        float* o = &outp[(((b * 16 + h) * 512) + s) * 16 + d0];
        float4 o1 = make_float4(acc[i][0] + bl[0], acc[i][1] + bl[1],
                                acc[i][2] + bl[2], acc[i][3] + bl[3]);
        float4 o2 = make_float4(acc[i][4] + bl[4], acc[i][5] + bl[5],
                                acc[i][6] + bl[6], acc[i][7] + bl[7]);
        *(float4*)&o[0] = o1;
        *(float4*)&o[4] = o2;
    }
}

// ---------------------------------------------------------------------------
// Attention: one block per (b,h). K,V,mask staged in LDS (fp32, 66 KB).
// Each thread owns 2 query rows (s = t, t+256), streams 512 keys.
// Unstabilized exp-score softmax exactly as reference:
//   e = exp(q.k/4) * mask[j];  ctx = sum(e*v) / (sum(e) + 1e-8)
// ---------------------------------------------------------------------------
__global__ __launch_bounds__(256, 2) void attn_kernel(
    const float* __restrict__ qp, const float* __restrict__ kp,
    const float* __restrict__ vp, const float* __restrict__ mask,
    float* __restrict__ out)
{
    const int bh = blockIdx.x;       // b*16 + h
    const int b = bh >> 4, h = bh & 15;

    __shared__ float ks[512][16];
    __shared__ float vs[512][16];
    __shared__ float ms[512];

    const int t = threadIdx.x;
    {
        const float* kb = kp + (size_t)bh * 8192;
        const float* vb = vp + (size_t)bh * 8192;
        float* ksf = &ks[0][0];
        float* vsf = &vs[0][0];
#pragma unroll
        for (int i = 0; i < 8; i++) {
            int f4 = (t + i * 256) * 4;   // 2048 float4s
            *(float4*)&ksf[f4] = *(const float4*)&kb[f4];
            *(float4*)&vsf[f4] = *(const float4*)&vb[f4];
        }
        if (t < 128)
            *(float4*)&ms[t * 4] = *(const float4*)&mask[b * 512 + t * 4];
    }

    float q0[16], q1[16], a0[16], a1[16];
    {
        const float* qb = qp + (size_t)bh * 8192;
#pragma unroll
        for (int i = 0; i < 4; i++) {
            *(float4*)&q0[i * 4] = *(const float4*)&qb[(t      ) * 16 + i * 4];
            *(float4*)&q1[i * 4] = *(const float4*)&qb[(t + 256) * 16 + i * 4];
        }
    }
#pragma unroll
    for (int i = 0; i < 16; i++) { a0[i] = 0.f; a1[i] = 0.f; }
    float s0 = 0.f, s1 = 0.f;

    __syncthreads();

#pragma unroll 2
    for (int j = 0; j < 512; j++) {
        float kj[16], vj[16];
#pragma unroll
        for (int i = 0; i < 4; i++)
            *(float4*)&kj[i * 4] = *(const float4*)&ks[j][i * 4];

        float d0a = 0.f, d0b = 0.f, d0c = 0.f, d0d = 0.f;
        float d1a = 0.f, d1b = 0.f, d1c = 0.f, d1d = 0.f;
#pragma unroll
        for (int i = 0; i < 4; i++) {
            d0a += q0[i]      * kj[i];
            d0b += q0[4 + i]  * kj[4 + i];
            d0c += q0[8 + i]  * kj[8 + i];
            d0d += q0[12 + i] * kj[12 + i];
            d1a += q1[i]      * kj[i];
            d1b += q1[4 + i]  * kj[4 + i];
            d1c += q1[8 + i]  * kj[8 + i];
            d1d += q1[12 + i] * kj[12 + i];
        }
        float d0 = (d0a + d0b) + (d0c + d0d);
        float d1 = (d1a + d1b) + (d1c + d1d);
        float m = ms[j];
        float e0 = __expf(d0 * 0.25f) * m;
        float e1 = __expf(d1 * 0.25f) * m;
        s0 += e0; s1 += e1;

#pragma unroll
        for (int i = 0; i < 4; i++)
            *(float4*)&vj[i * 4] = *(const float4*)&vs[j][i * 4];
#pragma unroll
        for (int i = 0; i < 16; i++) {
            a0[i] += e0 * vj[i];
            a1[i] += e1 * vj[i];
        }
    }

    float r0 = 1.f / (s0 + 1e-8f);
    float r1 = 1.f / (s1 + 1e-8f);

    float* o0 = out + ((size_t)(b * 512 + t      ) * 256) + h * 16;
    float* o1 = out + ((size_t)(b * 512 + t + 256) * 256) + h * 16;
#pragma unroll
    for (int i = 0; i < 4; i++) {
        *(float4*)&o0[i * 4] = make_float4(a0[i * 4] * r0, a0[i * 4 + 1] * r0,
                                           a0[i * 4 + 2] * r0, a0[i * 4 + 3] * r0);
        *(float4*)&o1[i * 4] = make_float4(a1[i * 4] * r1, a1[i * 4 + 1] * r1,
                                           a1[i * 4 + 2] * r1, a1[i * 4 + 3] * r1);
    }
}

extern "C" void kernel_launch(void* const* d_in, const int* in_sizes, int n_in,
                              void* d_out, int out_size, void* d_ws, size_t ws_size,
                              hipStream_t stream) {
    const float* Q    = (const float*)d_in[0];
    const float* K    = (const float*)d_in[1];
    const float* V    = (const float*)d_in[2];
    const float* mask = (const float*)d_in[3];
    const float* W_Q  = (const float*)d_in[4];
    const float* b_Q  = (const float*)d_in[5];
    const float* W_K  = (const float*)d_in[6];
    const float* b_K  = (const float*)d_in[7];
    const float* W_V  = (const float*)d_in[8];
    const float* b_V  = (const float*)d_in[9];
    float* out = (float*)d_out;

    float* qp = (float*)d_ws;              // [B,H,S,D] 16.78 MB
    float* kp = qp + PROJ_ELEMS;
    float* vp = kp + PROJ_ELEMS;           // total 50.3 MB of d_ws

    // 3 projections: grid (row tiles, col tiles, proj)
    proj_kernel<<<dim3(128, 2, 3), 256, 0, stream>>>(
        Q, K, V, W_Q, b_Q, W_K, b_K, W_V, b_V, qp, kp, vp);

    // attention: one block per (b,h)
    attn_kernel<<<dim3(32 * 16), 256, 0, stream>>>(qp, kp, vp, mask, out);
}

// Round 6
// 240.010 us; speedup vs baseline: 1.4691x; 1.4691x over previous
//
#include <hip/hip_runtime.h>
#include <hip/hip_bf16.h>

// B=32, S=512, D_MODEL=256, H=16, D_K=D_V=16
// Strategy: fp32 VALU projections (unchanged GEMM core) -> f16 outputs with
// folds (Q pre-scaled by 0.25*log2e, V stored transposed). Attention fully on
// MFMA f16: S^T = K*Q^T so QK output layout == PV A-fragment layout.

#define PROJ_ELEMS (32 * 16 * 512 * 16) // 4,194,304 elems per projected tensor

typedef _Float16 f16x4 __attribute__((ext_vector_type(4)));
typedef float    f32x4 __attribute__((ext_vector_type(4)));

// ---------------------------------------------------------------------------
// Projection GEMM (fp32 core): y[row][c] = sum_d X[row][d] * W[c][d] + b[c]
// rows = 16384, cols = 256, K = 256. Tile 128x128, BK=32, 8x8 micro-tile.
// Epilogue: proj 0 (Q): *(0.25*log2e) -> qh [bh][s][16] f16
//           proj 1 (K): kh [bh][s][16] f16
//           proj 2 (V): vth [bh][d][s] f16 (transposed for PV B-frag reads)
// ---------------------------------------------------------------------------
__global__ __launch_bounds__(256, 4) void proj_kernel(
    const float* __restrict__ Qx, const float* __restrict__ Kx, const float* __restrict__ Vx,
    const float* __restrict__ WQ, const float* __restrict__ bQ,
    const float* __restrict__ WK, const float* __restrict__ bK,
    const float* __restrict__ WV, const float* __restrict__ bV,
    _Float16* __restrict__ qh, _Float16* __restrict__ kh, _Float16* __restrict__ vth)
{
    const int proj = blockIdx.z;
    const float* __restrict__ X  = (proj == 0) ? Qx : (proj == 1) ? Kx : Vx;
    const float* __restrict__ W  = (proj == 0) ? WQ : (proj == 1) ? WK : WV;
    const float* __restrict__ bb = (proj == 0) ? bQ : (proj == 1) ? bK : bV;

    const int row0 = blockIdx.x * 128;
    const int col0 = blockIdx.y * 128;
    const int t  = threadIdx.x;
    const int tc = t & 15;   // col group (8 cols)
    const int tr = t >> 4;   // row group (8 rows)

    __shared__ float xs[32][132];
    __shared__ float wsh[32][132];

    float acc[8][8];
#pragma unroll
    for (int i = 0; i < 8; i++)
#pragma unroll
        for (int j = 0; j < 8; j++) acc[i][j] = 0.f;

    for (int k0 = 0; k0 < 256; k0 += 32) {
        __syncthreads();
#pragma unroll
        for (int i = 0; i < 4; i++) {
            int f = t + i * 256;
            int r = f >> 3, kq = f & 7;
            float4 xv = *(const float4*)&X[(row0 + r) * 256 + k0 + kq * 4];
            float4 wv = *(const float4*)&W[(col0 + r) * 256 + k0 + kq * 4];
            xs[kq * 4 + 0][r] = xv.x; xs[kq * 4 + 1][r] = xv.y;
            xs[kq * 4 + 2][r] = xv.z; xs[kq * 4 + 3][r] = xv.w;
            wsh[kq * 4 + 0][r] = wv.x; wsh[kq * 4 + 1][r] = wv.y;
            wsh[kq * 4 + 2][r] = wv.z; wsh[kq * 4 + 3][r] = wv.w;
        }
        __syncthreads();
#pragma unroll 8
        for (int kk = 0; kk < 32; kk++) {
            float4 xa = *(const float4*)&xs[kk][tr * 8];
            float4 xb = *(const float4*)&xs[kk][tr * 8 + 4];
            float4 wa = *(const float4*)&wsh[kk][tc * 8];
            float4 wb = *(const float4*)&wsh[kk][tc * 8 + 4];
            float xr[8] = {xa.x, xa.y, xa.z, xa.w, xb.x, xb.y, xb.z, xb.w};
            float wr[8] = {wa.x, wa.y, wa.z, wa.w, wb.x, wb.y, wb.z, wb.w};
#pragma unroll
            for (int i = 0; i < 8; i++)
#pragma unroll
                for (int j = 0; j < 8; j++) acc[i][j] += xr[i] * wr[j];
        }
    }

    const int c0 = col0 + tc * 8;   // 8 cols, all within one head
    const int h  = c0 >> 4;
    const int d0 = c0 & 15;         // 0 or 8
    float bl[8];
#pragma unroll
    for (int j = 0; j < 8; j++) bl[j] = bb[c0 + j];

    const int bq = row0 >> 9;
    const int s0 = (row0 & 511) + tr * 8;   // 8 consecutive s, same b

    if (proj < 2) {
        // q gets 0.25 (score scale) * log2(e) (exp->exp2 fold)
        const float scl = (proj == 0) ? 0.25f * 1.44269504088896f : 1.0f;
        _Float16* outp = (proj == 0) ? qh : kh;
#pragma unroll
        for (int i = 0; i < 8; i++) {
            _Float16 tmp[8];
#pragma unroll
            for (int j = 0; j < 8; j++) tmp[j] = (_Float16)((acc[i][j] + bl[j]) * scl);
            *(float4*)&outp[(((size_t)bq * 16 + h) * 512 + (s0 + i)) * 16 + d0] =
                *(const float4*)tmp;
        }
    } else {
        // vth[bh][d][s]: pack 8 consecutive s per column d
#pragma unroll
        for (int j = 0; j < 8; j++) {
            _Float16 tmp[8];
#pragma unroll
            for (int i = 0; i < 8; i++) tmp[i] = (_Float16)(acc[i][j] + bl[j]);
            *(float4*)&vth[(((size_t)bq * 16 + h) * 16 + (d0 + j)) * 512 + s0] =
                *(const float4*)tmp;
        }
    }
}

// ---------------------------------------------------------------------------
// MFMA attention. Block = (bh, half): 4 waves, each owns 64 q-rows (4 m-tiles).
// Per j-tile(16 keys): S^T tile = mfma(A=K, B=Q, C=log2(mask)) -> exp2 ->
// in-register P (layout == PV A-frag) -> ctx += mfma(P, V).
// Rowsum: per-lane partials + shfl_xor(16,32); normalize in epilogue.
// ---------------------------------------------------------------------------
__global__ __launch_bounds__(256, 4) void attn_mfma(
    const _Float16* __restrict__ qh, const _Float16* __restrict__ kh,
    const _Float16* __restrict__ vth, const float* __restrict__ mask,
    float* __restrict__ out)
{
    const int blk  = blockIdx.x;     // bh*2 + half
    const int bh   = blk >> 1;
    const int half = blk & 1;
    const int b = bh >> 4, h = bh & 15;

    __shared__ _Float16 ks[512 * 16];   // [s][16] 16 KB
    __shared__ _Float16 vt[16 * 528];   // [d][528] padded, 16.5 KB
    __shared__ float    lm[512];        // log2(mask)
    __shared__ float    sums[256];      // [wave][64 rowsums]

    const int t = threadIdx.x;
    const int w = t >> 6, l = t & 63;
    const int lm16 = l & 15, lg = l >> 4;

    {   // stage K (linear)
        const float4* src = (const float4*)(kh + (size_t)bh * 8192);
        float4* dst = (float4*)ks;
#pragma unroll
        for (int i = 0; i < 4; i++) dst[t + i * 256] = src[t + i * 256];
    }
    {   // stage V^T with row pad 512->528
        const _Float16* src = vth + (size_t)bh * 8192;
#pragma unroll
        for (int i = 0; i < 4; i++) {
            int f = t + i * 256;           // 1024 chunks of 8 f16
            int d = f >> 6, c = f & 63;
            *(float4*)&vt[d * 528 + c * 8] = *(const float4*)&src[d * 512 + c * 8];
        }
    }
    {   // mask -> log2 (log2(0) = -inf -> exp2 = 0, exact)
#pragma unroll
        for (int i = 0; i < 2; i++) {
            int j = t + i * 256;
            lm[j] = __builtin_amdgcn_logf(mask[b * 512 + j]);
        }
    }

    // preload Q B-fragments: lane supplies Q[m0 + (l&15)][(l>>4)*4 + i]
    f16x4 qf[4];
    {
        const _Float16* qb = qh + (size_t)bh * 8192;
#pragma unroll
        for (int mt = 0; mt < 4; mt++) {
            int m = half * 256 + w * 64 + mt * 16 + lm16;
            qf[mt] = *(const f16x4*)&qb[m * 16 + lg * 4];
        }
    }

    f32x4 acc[4];
    float rs[4];
#pragma unroll
    for (int mt = 0; mt < 4; mt++) {
        acc[mt] = (f32x4){0.f, 0.f, 0.f, 0.f};
        rs[mt] = 0.f;
    }

    __syncthreads();

    for (int jt = 0; jt < 32; jt++) {
        const int j0 = jt << 4;
        // A-frag K: lane -> K[j0+(l&15)][(l>>4)*4+i]
        f16x4 ka = *(const f16x4*)&ks[(j0 + lm16) * 16 + lg * 4];
        // B-frag V: lane -> V[j0+(l>>4)*4+i][d=l&15] = vt[l&15][j0+(l>>4)*4+i]
        f16x4 vb = *(const f16x4*)&vt[lm16 * 528 + j0 + lg * 4];
        // C-init: lane reg r is row j0+(l>>4)*4+r -> lm[j0+lg*4+r]
        f32x4 lmv = *(const f32x4*)&lm[j0 + lg * 4];
#pragma unroll
        for (int mt = 0; mt < 4; mt++) {
            f32x4 s4 = __builtin_amdgcn_mfma_f32_16x16x16f16(ka, qf[mt], lmv, 0, 0, 0);
            float e0 = __builtin_amdgcn_exp2f(s4[0]);
            float e1 = __builtin_amdgcn_exp2f(s4[1]);
            float e2 = __builtin_amdgcn_exp2f(s4[2]);
            float e3 = __builtin_amdgcn_exp2f(s4[3]);
            rs[mt] += (e0 + e1) + (e2 + e3);
            f16x4 pa;
            pa[0] = (_Float16)e0; pa[1] = (_Float16)e1;
            pa[2] = (_Float16)e2; pa[3] = (_Float16)e3;
            acc[mt] = __builtin_amdgcn_mfma_f32_16x16x16f16(pa, vb, acc[mt], 0, 0, 0);
        }
    }

    // rowsum: lanes {m, m+16, m+32, m+48} hold partials for col m = l&15
#pragma unroll
    for (int mt = 0; mt < 4; mt++) {
        float r = rs[mt];
        r += __shfl_xor(r, 16);
        r += __shfl_xor(r, 32);
        if (l < 16) sums[w * 64 + mt * 16 + l] = r;
    }
    __syncthreads();

#pragma unroll
    for (int mt = 0; mt < 4; mt++) {
        f32x4 sv = *(const f32x4*)&sums[w * 64 + mt * 16 + lg * 4];
        int m = half * 256 + w * 64 + mt * 16 + lg * 4;
        float* o = out + ((size_t)(b * 512 + m) * 256) + h * 16 + lm16;
        o[0]   = acc[mt][0] / (sv[0] + 1e-8f);
        o[256] = acc[mt][1] / (sv[1] + 1e-8f);
        o[512] = acc[mt][2] / (sv[2] + 1e-8f);
        o[768] = acc[mt][3] / (sv[3] + 1e-8f);
    }
}

extern "C" void kernel_launch(void* const* d_in, const int* in_sizes, int n_in,
                              void* d_out, int out_size, void* d_ws, size_t ws_size,
                              hipStream_t stream) {
    const float* Q    = (const float*)d_in[0];
    const float* K    = (const float*)d_in[1];
    const float* V    = (const float*)d_in[2];
    const float* mask = (const float*)d_in[3];
    const float* W_Q  = (const float*)d_in[4];
    const float* b_Q  = (const float*)d_in[5];
    const float* W_K  = (const float*)d_in[6];
    const float* b_K  = (const float*)d_in[7];
    const float* W_V  = (const float*)d_in[8];
    const float* b_V  = (const float*)d_in[9];
    float* out = (float*)d_out;

    _Float16* qh  = (_Float16*)d_ws;            // [bh][s][16], pre-scaled
    _Float16* kh  = qh + PROJ_ELEMS;            // [bh][s][16]
    _Float16* vth = kh + PROJ_ELEMS;            // [bh][d][s]

    proj_kernel<<<dim3(128, 2, 3), 256, 0, stream>>>(
        Q, K, V, W_Q, b_Q, W_K, b_K, W_V, b_V, qh, kh, vth);

    attn_mfma<<<dim3(32 * 16 * 2), 256, 0, stream>>>(qh, kh, vth, mask, out);
}

// Round 8
// 182.508 us; speedup vs baseline: 1.9319x; 1.3151x over previous
//
#include <hip/hip_runtime.h>
#include <hip/hip_bf16.h>

// B=32, S=512, D_MODEL=256, H=16, D_K=D_V=16
// proj_mfma: all three projections on MFMA f16 (fp32 accum), f16 outputs with
// folds (Q pre-scaled by 0.25*log2e, V stored transposed).
// attn_mfma: unchanged from round 6 (S^T = K*Q^T swapped-operand flash-style).

#define PROJ_ELEMS (32 * 16 * 512 * 16) // 4,194,304 elems per projected tensor
#define LOG2E 1.44269504088896f

typedef _Float16 f16x4 __attribute__((ext_vector_type(4)));
typedef float    f32x4 __attribute__((ext_vector_type(4)));

static __device__ __forceinline__ f16x4 cvt4(float4 v) {
    f16x4 r;
    r[0] = (_Float16)v.x; r[1] = (_Float16)v.y;
    r[2] = (_Float16)v.z; r[3] = (_Float16)v.w;
    return r;
}

// ---------------------------------------------------------------------------
// MFMA projection. Block = 64 rows x 256 cols, BK=64, 4 waves (wave w owns
// col strip w*64..w*64+63 = 4 n-tiles; 4 m-tiles of rows). mfma_f32_16x16x16f16
// lane algebra (verified by round-6 attn): D row i=(l>>4)*4+r comes from the
// A operand's row, D col j=l&15 from the B operand's row; both A/B frags read
// [l&15] row, [(l>>4)*4..+3] k. Q/K: A=W,B=X -> lane packs 4 consecutive d.
// V: A=X,B=W -> lane packs 4 consecutive s (for vth [d][s]).
// ---------------------------------------------------------------------------
__global__ __launch_bounds__(256, 3) void proj_mfma(
    const float* __restrict__ Qx, const float* __restrict__ Kx, const float* __restrict__ Vx,
    const float* __restrict__ WQ, const float* __restrict__ bQ,
    const float* __restrict__ WK, const float* __restrict__ bK,
    const float* __restrict__ WV, const float* __restrict__ bV,
    _Float16* __restrict__ qh, _Float16* __restrict__ kh, _Float16* __restrict__ vth)
{
    const int proj = blockIdx.z;
    const float* __restrict__ X  = (proj == 0) ? Qx : (proj == 1) ? Kx : Vx;
    const float* __restrict__ W  = (proj == 0) ? WQ : (proj == 1) ? WK : WV;
    const float* __restrict__ bb = (proj == 0) ? bQ : (proj == 1) ? bK : bV;

    const int row0 = blockIdx.x * 64;     // global row (b*512+s), no b-crossing
    const int t = threadIdx.x;
    const int w = t >> 6, l = t & 63;
    const int lm16 = l & 15, lg = l >> 4;

    __shared__ _Float16 xs[64][72];       // row-pad 72 f16 = 144B (bank rotate)
    __shared__ _Float16 wsh[256][72];
    __shared__ float bl[256];

    bl[t] = bb[t];

    f32x4 acc[4][4];                      // [mi][ni]
#pragma unroll
    for (int mi = 0; mi < 4; mi++)
#pragma unroll
        for (int ni = 0; ni < 4; ni++) acc[mi][ni] = (f32x4){0.f, 0.f, 0.f, 0.f};

    for (int k0 = 0; k0 < 256; k0 += 64) {
        __syncthreads();
        // stage X tile 64x64 -> f16 (coalesced: 16 lanes cover one row's 64 k)
#pragma unroll
        for (int i = 0; i < 4; i++) {
            int f4 = t + i * 256;
            int r = f4 >> 4, kq = f4 & 15;
            float4 xv = *(const float4*)&X[(size_t)(row0 + r) * 256 + k0 + kq * 4];
            *(f16x4*)&xs[r][kq * 4] = cvt4(xv);
        }
        // stage W tile 256x64 -> f16
#pragma unroll
        for (int i = 0; i < 16; i++) {
            int f4 = t + i * 256;
            int r = f4 >> 4, kq = f4 & 15;
            float4 wv = *(const float4*)&W[(size_t)r * 256 + k0 + kq * 4];
            *(f16x4*)&wsh[r][kq * 4] = cvt4(wv);
        }
        __syncthreads();

#pragma unroll
        for (int kq = 0; kq < 4; kq++) {  // 16-wide k slices within BK=64
            f16x4 xf[4], wf[4];
#pragma unroll
            for (int mi = 0; mi < 4; mi++)
                xf[mi] = *(const f16x4*)&xs[mi * 16 + lm16][kq * 16 + lg * 4];
#pragma unroll
            for (int ni = 0; ni < 4; ni++)
                wf[ni] = *(const f16x4*)&wsh[w * 64 + ni * 16 + lm16][kq * 16 + lg * 4];

            if (proj < 2) {
#pragma unroll
                for (int mi = 0; mi < 4; mi++)
#pragma unroll
                    for (int ni = 0; ni < 4; ni++)
                        acc[mi][ni] = __builtin_amdgcn_mfma_f32_16x16x16f16(
                            wf[ni], xf[mi], acc[mi][ni], 0, 0, 0);
            } else {
#pragma unroll
                for (int mi = 0; mi < 4; mi++)
#pragma unroll
                    for (int ni = 0; ni < 4; ni++)
                        acc[mi][ni] = __builtin_amdgcn_mfma_f32_16x16x16f16(
                            xf[mi], wf[ni], acc[mi][ni], 0, 0, 0);
            }
        }
    }

    const int bq = row0 >> 9;
    const int sbase = row0 & 511;

    if (proj < 2) {
        // D row = W col (lane: d0+r, 4 consecutive), D col = X row (lm16)
        const float scl = (proj == 0) ? 0.25f * LOG2E : 1.0f;
        _Float16* __restrict__ outp = (proj == 0) ? qh : kh;
#pragma unroll
        for (int mi = 0; mi < 4; mi++) {
            const int s = sbase + mi * 16 + lm16;
#pragma unroll
            for (int ni = 0; ni < 4; ni++) {
                const int col0 = w * 64 + ni * 16 + lg * 4;   // head-aligned
                const int h = col0 >> 4, d0 = col0 & 15;
                _Float16 tmp[4];
#pragma unroll
                for (int r = 0; r < 4; r++)
                    tmp[r] = (_Float16)((acc[mi][ni][r] + bl[col0 + r]) * scl);
                *(f16x4*)&outp[(((size_t)bq * 16 + h) * 512 + s) * 16 + d0] =
                    *(const f16x4*)tmp;
            }
        }
    } else {
        // D row = X row (lane: s0+r, 4 consecutive), D col = W col (lm16)
#pragma unroll
        for (int mi = 0; mi < 4; mi++) {
            const int s0 = sbase + mi * 16 + lg * 4;
#pragma unroll
            for (int ni = 0; ni < 4; ni++) {
                const int col = w * 64 + ni * 16 + lm16;
                const int h = col >> 4, d = col & 15;
                const float bc = bl[col];
                _Float16 tmp[4];
#pragma unroll
                for (int r = 0; r < 4; r++)
                    tmp[r] = (_Float16)(acc[mi][ni][r] + bc);
                *(f16x4*)&vth[(((size_t)bq * 16 + h) * 16 + d) * 512 + s0] =
                    *(const f16x4*)tmp;
            }
        }
    }
}

// ---------------------------------------------------------------------------
// MFMA attention (unchanged from round 6). Block = (bh, half): 4 waves, each
// owns 64 q-rows. Per j-tile: S^T = mfma(A=K, B=Q, C=log2(mask)) -> exp2 ->
// P in-register (== PV A-frag layout) -> ctx += mfma(P, V).
// ---------------------------------------------------------------------------
__global__ __launch_bounds__(256, 4) void attn_mfma(
    const _Float16* __restrict__ qh, const _Float16* __restrict__ kh,
    const _Float16* __restrict__ vth, const float* __restrict__ mask,
    float* __restrict__ out)
{
    const int blk  = blockIdx.x;     // bh*2 + half
    const int bh   = blk >> 1;
    const int half = blk & 1;
    const int b = bh >> 4, h = bh & 15;

    __shared__ _Float16 ks[512 * 16];   // [s][16] 16 KB
    __shared__ _Float16 vt[16 * 528];   // [d][528] padded, 16.5 KB
    __shared__ float    lm[512];        // log2(mask)
    __shared__ float    sums[256];      // [wave][64 rowsums]

    const int t = threadIdx.x;
    const int w = t >> 6, l = t & 63;
    const int lm16 = l & 15, lg = l >> 4;

    {   // stage K (linear)
        const float4* src = (const float4*)(kh + (size_t)bh * 8192);
        float4* dst = (float4*)ks;
#pragma unroll
        for (int i = 0; i < 4; i++) dst[t + i * 256] = src[t + i * 256];
    }
    {   // stage V^T with row pad 512->528
        const _Float16* src = vth + (size_t)bh * 8192;
#pragma unroll
        for (int i = 0; i < 4; i++) {
            int f = t + i * 256;           // 1024 chunks of 8 f16
            int d = f >> 6, c = f & 63;
            *(float4*)&vt[d * 528 + c * 8] = *(const float4*)&src[d * 512 + c * 8];
        }
    }
    {   // mask -> log2 (log2(0) = -inf -> exp2 = 0, exact)
#pragma unroll
        for (int i = 0; i < 2; i++) {
            int j = t + i * 256;
            lm[j] = __builtin_amdgcn_logf(mask[b * 512 + j]);
        }
    }

    // preload Q B-fragments: lane supplies Q[m0 + (l&15)][(l>>4)*4 + i]
    f16x4 qf[4];
    {
        const _Float16* qb = qh + (size_t)bh * 8192;
#pragma unroll
        for (int mt = 0; mt < 4; mt++) {
            int m = half * 256 + w * 64 + mt * 16 + lm16;
            qf[mt] = *(const f16x4*)&qb[m * 16 + lg * 4];
        }
    }

    f32x4 acc[4];
    float rs[4];
#pragma unroll
    for (int mt = 0; mt < 4; mt++) {
        acc[mt] = (f32x4){0.f, 0.f, 0.f, 0.f};
        rs[mt] = 0.f;
    }

    __syncthreads();

    for (int jt = 0; jt < 32; jt++) {
        const int j0 = jt << 4;
        f16x4 ka = *(const f16x4*)&ks[(j0 + lm16) * 16 + lg * 4];
        f16x4 vb = *(const f16x4*)&vt[lm16 * 528 + j0 + lg * 4];
        f32x4 lmv = *(const f32x4*)&lm[j0 + lg * 4];
#pragma unroll
        for (int mt = 0; mt < 4; mt++) {
            f32x4 s4 = __builtin_amdgcn_mfma_f32_16x16x16f16(ka, qf[mt], lmv, 0, 0, 0);
            float e0 = __builtin_amdgcn_exp2f(s4[0]);
            float e1 = __builtin_amdgcn_exp2f(s4[1]);
            float e2 = __builtin_amdgcn_exp2f(s4[2]);
            float e3 = __builtin_amdgcn_exp2f(s4[3]);
            rs[mt] += (e0 + e1) + (e2 + e3);
            f16x4 pa;
            pa[0] = (_Float16)e0; pa[1] = (_Float16)e1;
            pa[2] = (_Float16)e2; pa[3] = (_Float16)e3;
            acc[mt] = __builtin_amdgcn_mfma_f32_16x16x16f16(pa, vb, acc[mt], 0, 0, 0);
        }
    }

    // rowsum: lanes {m, m+16, m+32, m+48} hold partials for col m = l&15
#pragma unroll
    for (int mt = 0; mt < 4; mt++) {
        float r = rs[mt];
        r += __shfl_xor(r, 16);
        r += __shfl_xor(r, 32);
        if (l < 16) sums[w * 64 + mt * 16 + l] = r;
    }
    __syncthreads();

#pragma unroll
    for (int mt = 0; mt < 4; mt++) {
        f32x4 sv = *(const f32x4*)&sums[w * 64 + mt * 16 + lg * 4];
        int m = half * 256 + w * 64 + mt * 16 + lg * 4;
        float* o = out + ((size_t)(b * 512 + m) * 256) + h * 16 + lm16;
        o[0]   = acc[mt][0] / (sv[0] + 1e-8f);
        o[256] = acc[mt][1] / (sv[1] + 1e-8f);
        o[512] = acc[mt][2] / (sv[2] + 1e-8f);
        o[768] = acc[mt][3] / (sv[3] + 1e-8f);
    }
}

extern "C" void kernel_launch(void* const* d_in, const int* in_sizes, int n_in,
                              void* d_out, int out_size, void* d_ws, size_t ws_size,
                              hipStream_t stream) {
    const float* Q    = (const float*)d_in[0];
    const float* K    = (const float*)d_in[1];
    const float* V    = (const float*)d_in[2];
    const float* mask = (const float*)d_in[3];
    const float* W_Q  = (const float*)d_in[4];
    const float* b_Q  = (const float*)d_in[5];
    const float* W_K  = (const float*)d_in[6];
    const float* b_K  = (const float*)d_in[7];
    const float* W_V  = (const float*)d_in[8];
    const float* b_V  = (const float*)d_in[9];
    float* out = (float*)d_out;

    _Float16* qh  = (_Float16*)d_ws;            // [bh][s][16], pre-scaled
    _Float16* kh  = qh + PROJ_ELEMS;            // [bh][s][16]
    _Float16* vth = kh + PROJ_ELEMS;            // [bh][d][s]

    proj_mfma<<<dim3(256, 1, 3), 256, 0, stream>>>(
        Q, K, V, W_Q, b_Q, W_K, b_K, W_V, b_V, qh, kh, vth);

    attn_mfma<<<dim3(32 * 16 * 2), 256, 0, stream>>>(qh, kh, vth, mask, out);
}

// Round 10
// 180.558 us; speedup vs baseline: 1.9528x; 1.0108x over previous
//
#include <hip/hip_runtime.h>
#include <hip/hip_bf16.h>

// B=32, S=512, D_MODEL=256, H=16, D_K=D_V=16
// proj_mfma v3: all-register streaming MFMA GEMM — no LDS, no barriers.
// Both A/B fragments load 16B of consecutive fp32 from global (coalesced in
// 64B segments across lg lanes), cvt to f16 in-reg. W is L2-resident after
// first touch (256KB/proj); X streams from HBM once.
// attn_mfma: unchanged (verified rounds 6/8).

#define PROJ_ELEMS (32 * 16 * 512 * 16) // 4,194,304 elems per projected tensor
#define LOG2E 1.44269504088896f

typedef _Float16 f16x4 __attribute__((ext_vector_type(4)));
typedef float    f32x4 __attribute__((ext_vector_type(4)));

static __device__ __forceinline__ f16x4 cvt4(float4 v) {
    f16x4 r;
    r[0] = (_Float16)v.x; r[1] = (_Float16)v.y;
    r[2] = (_Float16)v.z; r[3] = (_Float16)v.w;
    return r;
}

// ---------------------------------------------------------------------------
// Block = 64 rows x 256 cols, 4 waves (wave w owns col strip w*64: 4 n-tiles;
// 4 m-tiles of rows). Same mfma_f32_16x16x16f16 lane algebra as round 8
// (verified): D row from A operand's row, D col from B operand's row; A/B
// frag = operand[l&15-th row][(l>>4)*4 .. +3 of k].
// Q/K: A=W, B=X -> lane packs 4 consecutive d.  V: A=X, B=W -> 4 consecutive s.
// ---------------------------------------------------------------------------
__global__ __launch_bounds__(256, 2) void proj_mfma(
    const float* __restrict__ Qx, const float* __restrict__ Kx, const float* __restrict__ Vx,
    const float* __restrict__ WQ, const float* __restrict__ bQ,
    const float* __restrict__ WK, const float* __restrict__ bK,
    const float* __restrict__ WV, const float* __restrict__ bV,
    _Float16* __restrict__ qh, _Float16* __restrict__ kh, _Float16* __restrict__ vth)
{
    const int proj = blockIdx.z;
    const float* __restrict__ X  = (proj == 0) ? Qx : (proj == 1) ? Kx : Vx;
    const float* __restrict__ W  = (proj == 0) ? WQ : (proj == 1) ? WK : WV;
    const float* __restrict__ bb = (proj == 0) ? bQ : (proj == 1) ? bK : bV;

    const int row0 = blockIdx.x * 64;     // global row (b*512+s), no b-crossing
    const int t = threadIdx.x;
    const int w = t >> 6, l = t & 63;
    const int lm16 = l & 15, lg = l >> 4;

    // per-fragment global base pointers (16B-aligned)
    const float* xbase[4];
    const float* wbase[4];
#pragma unroll
    for (int mi = 0; mi < 4; mi++)
        xbase[mi] = X + (size_t)(row0 + mi * 16 + lm16) * 256 + lg * 4;
#pragma unroll
    for (int ni = 0; ni < 4; ni++)
        wbase[ni] = W + (size_t)(w * 64 + ni * 16 + lm16) * 256 + lg * 4;

    f32x4 acc[4][4];                      // [mi][ni]
#pragma unroll
    for (int mi = 0; mi < 4; mi++)
#pragma unroll
        for (int ni = 0; ni < 4; ni++) acc[mi][ni] = (f32x4){0.f, 0.f, 0.f, 0.f};

#pragma unroll 1
    for (int k0 = 0; k0 < 256; k0 += 64) {
        // load all 32 fragments of this k-panel (independent -> deep MLP)
        float4 xr[4][4], wr[4][4];        // [kq][mi/ni]
#pragma unroll
        for (int kq = 0; kq < 4; kq++) {
#pragma unroll
            for (int mi = 0; mi < 4; mi++)
                xr[kq][mi] = *(const float4*)(xbase[mi] + k0 + kq * 16);
#pragma unroll
            for (int ni = 0; ni < 4; ni++)
                wr[kq][ni] = *(const float4*)(wbase[ni] + k0 + kq * 16);
        }
#pragma unroll
        for (int kq = 0; kq < 4; kq++) {
            f16x4 xf[4], wf[4];
#pragma unroll
            for (int mi = 0; mi < 4; mi++) xf[mi] = cvt4(xr[kq][mi]);
#pragma unroll
            for (int ni = 0; ni < 4; ni++) wf[ni] = cvt4(wr[kq][ni]);

            if (proj < 2) {
#pragma unroll
                for (int mi = 0; mi < 4; mi++)
#pragma unroll
                    for (int ni = 0; ni < 4; ni++)
                        acc[mi][ni] = __builtin_amdgcn_mfma_f32_16x16x16f16(
                            wf[ni], xf[mi], acc[mi][ni], 0, 0, 0);
            } else {
#pragma unroll
                for (int mi = 0; mi < 4; mi++)
#pragma unroll
                    for (int ni = 0; ni < 4; ni++)
                        acc[mi][ni] = __builtin_amdgcn_mfma_f32_16x16x16f16(
                            xf[mi], wf[ni], acc[mi][ni], 0, 0, 0);
            }
        }
    }

    const int bq = row0 >> 9;
    const int sbase = row0 & 511;

    if (proj < 2) {
        // D row = W col (lane: col0+r, 4 consecutive d), D col = X row (lm16)
        const float scl = (proj == 0) ? 0.25f * LOG2E : 1.0f;
        _Float16* __restrict__ outp = (proj == 0) ? qh : kh;
#pragma unroll
        for (int mi = 0; mi < 4; mi++) {
            const int s = sbase + mi * 16 + lm16;
#pragma unroll
            for (int ni = 0; ni < 4; ni++) {
                const int col0 = w * 64 + ni * 16 + lg * 4;   // head-aligned
                const int h = col0 >> 4, d0 = col0 & 15;
                const float4 bv = *(const float4*)&bb[col0];
                _Float16 tmp[4];
                tmp[0] = (_Float16)((acc[mi][ni][0] + bv.x) * scl);
                tmp[1] = (_Float16)((acc[mi][ni][1] + bv.y) * scl);
                tmp[2] = (_Float16)((acc[mi][ni][2] + bv.z) * scl);
                tmp[3] = (_Float16)((acc[mi][ni][3] + bv.w) * scl);
                *(f16x4*)&outp[(((size_t)bq * 16 + h) * 512 + s) * 16 + d0] =
                    *(const f16x4*)tmp;
            }
        }
    } else {
        // D row = X row (lane: s0+r, 4 consecutive s), D col = W col (lm16)
#pragma unroll
        for (int mi = 0; mi < 4; mi++) {
            const int s0 = sbase + mi * 16 + lg * 4;
#pragma unroll
            for (int ni = 0; ni < 4; ni++) {
                const int col = w * 64 + ni * 16 + lm16;
                const int h = col >> 4, d = col & 15;
                const float bc = bb[col];
                _Float16 tmp[4];
#pragma unroll
                for (int r = 0; r < 4; r++)
                    tmp[r] = (_Float16)(acc[mi][ni][r] + bc);
                *(f16x4*)&vth[(((size_t)bq * 16 + h) * 16 + d) * 512 + s0] =
                    *(const f16x4*)tmp;
            }
        }
    }
}

// ---------------------------------------------------------------------------
// MFMA attention (unchanged, verified). Block = (bh, half): 4 waves, each
// owns 64 q-rows. Per j-tile: S^T = mfma(A=K, B=Q, C=log2(mask)) -> exp2 ->
// P in-register (== PV A-frag layout) -> ctx += mfma(P, V).
// ---------------------------------------------------------------------------
__global__ __launch_bounds__(256, 4) void attn_mfma(
    const _Float16* __restrict__ qh, const _Float16* __restrict__ kh,
    const _Float16* __restrict__ vth, const float* __restrict__ mask,
    float* __restrict__ out)
{
    const int blk  = blockIdx.x;     // bh*2 + half
    const int bh   = blk >> 1;
    const int half = blk & 1;
    const int b = bh >> 4, h = bh & 15;

    __shared__ _Float16 ks[512 * 16];   // [s][16] 16 KB
    __shared__ _Float16 vt[16 * 528];   // [d][528] padded, 16.5 KB
    __shared__ float    lm[512];        // log2(mask)
    __shared__ float    sums[256];      // [wave][64 rowsums]

    const int t = threadIdx.x;
    const int w = t >> 6, l = t & 63;
    const int lm16 = l & 15, lg = l >> 4;

    {   // stage K (linear)
        const float4* src = (const float4*)(kh + (size_t)bh * 8192);
        float4* dst = (float4*)ks;
#pragma unroll
        for (int i = 0; i < 4; i++) dst[t + i * 256] = src[t + i * 256];
    }
    {   // stage V^T with row pad 512->528
        const _Float16* src = vth + (size_t)bh * 8192;
#pragma unroll
        for (int i = 0; i < 4; i++) {
            int f = t + i * 256;           // 1024 chunks of 8 f16
            int d = f >> 6, c = f & 63;
            *(float4*)&vt[d * 528 + c * 8] = *(const float4*)&src[d * 512 + c * 8];
        }
    }
    {   // mask -> log2 (log2(0) = -inf -> exp2 = 0, exact)
#pragma unroll
        for (int i = 0; i < 2; i++) {
            int j = t + i * 256;
            lm[j] = __builtin_amdgcn_logf(mask[b * 512 + j]);
        }
    }

    // preload Q B-fragments: lane supplies Q[m0 + (l&15)][(l>>4)*4 + i]
    f16x4 qf[4];
    {
        const _Float16* qb = qh + (size_t)bh * 8192;
#pragma unroll
        for (int mt = 0; mt < 4; mt++) {
            int m = half * 256 + w * 64 + mt * 16 + lm16;
            qf[mt] = *(const f16x4*)&qb[m * 16 + lg * 4];
        }
    }

    f32x4 acc[4];
    float rs[4];
#pragma unroll
    for (int mt = 0; mt < 4; mt++) {
        acc[mt] = (f32x4){0.f, 0.f, 0.f, 0.f};
        rs[mt] = 0.f;
    }

    __syncthreads();

    for (int jt = 0; jt < 32; jt++) {
        const int j0 = jt << 4;
        f16x4 ka = *(const f16x4*)&ks[(j0 + lm16) * 16 + lg * 4];
        f16x4 vb = *(const f16x4*)&vt[lm16 * 528 + j0 + lg * 4];
        f32x4 lmv = *(const f32x4*)&lm[j0 + lg * 4];
#pragma unroll
        for (int mt = 0; mt < 4; mt++) {
            f32x4 s4 = __builtin_amdgcn_mfma_f32_16x16x16f16(ka, qf[mt], lmv, 0, 0, 0);
            float e0 = __builtin_amdgcn_exp2f(s4[0]);
            float e1 = __builtin_amdgcn_exp2f(s4[1]);
            float e2 = __builtin_amdgcn_exp2f(s4[2]);
            float e3 = __builtin_amdgcn_exp2f(s4[3]);
            rs[mt] += (e0 + e1) + (e2 + e3);
            f16x4 pa;
            pa[0] = (_Float16)e0; pa[1] = (_Float16)e1;
            pa[2] = (_Float16)e2; pa[3] = (_Float16)e3;
            acc[mt] = __builtin_amdgcn_mfma_f32_16x16x16f16(pa, vb, acc[mt], 0, 0, 0);
        }
    }

    // rowsum: lanes {m, m+16, m+32, m+48} hold partials for col m = l&15
#pragma unroll
    for (int mt = 0; mt < 4; mt++) {
        float r = rs[mt];
        r += __shfl_xor(r, 16);
        r += __shfl_xor(r, 32);
        if (l < 16) sums[w * 64 + mt * 16 + l] = r;
    }
    __syncthreads();

#pragma unroll
    for (int mt = 0; mt < 4; mt++) {
        f32x4 sv = *(const f32x4*)&sums[w * 64 + mt * 16 + lg * 4];
        int m = half * 256 + w * 64 + mt * 16 + lg * 4;
        float* o = out + ((size_t)(b * 512 + m) * 256) + h * 16 + lm16;
        o[0]   = acc[mt][0] / (sv[0] + 1e-8f);
        o[256] = acc[mt][1] / (sv[1] + 1e-8f);
        o[512] = acc[mt][2] / (sv[2] + 1e-8f);
        o[768] = acc[mt][3] / (sv[3] + 1e-8f);
    }
}

extern "C" void kernel_launch(void* const* d_in, const int* in_sizes, int n_in,
                              void* d_out, int out_size, void* d_ws, size_t ws_size,
                              hipStream_t stream) {
    const float* Q    = (const float*)d_in[0];
    const float* K    = (const float*)d_in[1];
    const float* V    = (const float*)d_in[2];
    const float* mask = (const float*)d_in[3];
    const float* W_Q  = (const float*)d_in[4];
    const float* b_Q  = (const float*)d_in[5];
    const float* W_K  = (const float*)d_in[6];
    const float* b_K  = (const float*)d_in[7];
    const float* W_V  = (const float*)d_in[8];
    const float* b_V  = (const float*)d_in[9];
    float* out = (float*)d_out;

    _Float16* qh  = (_Float16*)d_ws;            // [bh][s][16], pre-scaled
    _Float16* kh  = qh + PROJ_ELEMS;            // [bh][s][16]
    _Float16* vth = kh + PROJ_ELEMS;            // [bh][d][s]

    proj_mfma<<<dim3(256, 1, 3), 256, 0, stream>>>(
        Q, K, V, W_Q, b_Q, W_K, b_K, W_V, b_V, qh, kh, vth);

    attn_mfma<<<dim3(32 * 16 * 2), 256, 0, stream>>>(qh, kh, vth, mask, out);
}

// Round 12
// 168.298 us; speedup vs baseline: 2.0950x; 1.0728x over previous
//
#include <hip/hip_runtime.h>
#include <hip/hip_bf16.h>

// B=32, S=512, D_MODEL=256, H=16, D_K=D_V=16
// proj_mfma v4: register-streaming MFMA GEMM with explicit ping-pong
// software pipeline (BK=16 slices, prefetch distance 1) so global loads
// overlap cvt+MFMA instead of serializing (round-10 lesson: VGPR=92 meant
// the compiler serialized 32 batched loads; named double buffers + unroll 1
// pin a ~160-VGPR schedule with loads in flight).
// attn_mfma: unchanged (verified rounds 6/8/10).

#define PROJ_ELEMS (32 * 16 * 512 * 16) // 4,194,304 elems per projected tensor
#define LOG2E 1.44269504088896f

typedef _Float16 f16x4 __attribute__((ext_vector_type(4)));
typedef float    f32x4 __attribute__((ext_vector_type(4)));

static __device__ __forceinline__ f16x4 cvt4(float4 v) {
    f16x4 r;
    r[0] = (_Float16)v.x; r[1] = (_Float16)v.y;
    r[2] = (_Float16)v.z; r[3] = (_Float16)v.w;
    return r;
}

// one 16-k slice: cvt 8 frags, 16 MFMAs into acc
static __device__ __forceinline__ void mfma_slice(
    int proj, const float4* xbuf, const float4* wbuf, f32x4 (*acc)[4])
{
    f16x4 xf[4], wf[4];
#pragma unroll
    for (int mi = 0; mi < 4; mi++) xf[mi] = cvt4(xbuf[mi]);
#pragma unroll
    for (int ni = 0; ni < 4; ni++) wf[ni] = cvt4(wbuf[ni]);
    if (proj < 2) {
#pragma unroll
        for (int mi = 0; mi < 4; mi++)
#pragma unroll
            for (int ni = 0; ni < 4; ni++)
                acc[mi][ni] = __builtin_amdgcn_mfma_f32_16x16x16f16(
                    wf[ni], xf[mi], acc[mi][ni], 0, 0, 0);
    } else {
#pragma unroll
        for (int mi = 0; mi < 4; mi++)
#pragma unroll
            for (int ni = 0; ni < 4; ni++)
                acc[mi][ni] = __builtin_amdgcn_mfma_f32_16x16x16f16(
                    xf[mi], wf[ni], acc[mi][ni], 0, 0, 0);
    }
}

// ---------------------------------------------------------------------------
// Block = 64 rows x 256 cols, 4 waves (wave w owns col strip w*64: 4 n-tiles;
// 4 m-tiles of rows). mfma_f32_16x16x16f16 lane algebra (verified r6/8/10):
// D row from A operand's row, D col from B operand's row; A/B frag =
// operand[l&15-th row][(l>>4)*4 .. +3 of k].
// Q/K: A=W, B=X -> lane packs 4 consecutive d.  V: A=X, B=W -> 4 consecutive s.
// ---------------------------------------------------------------------------
__global__ __launch_bounds__(256, 2) void proj_mfma(
    const float* __restrict__ Qx, const float* __restrict__ Kx, const float* __restrict__ Vx,
    const float* __restrict__ WQ, const float* __restrict__ bQ,
    const float* __restrict__ WK, const float* __restrict__ bK,
    const float* __restrict__ WV, const float* __restrict__ bV,
    _Float16* __restrict__ qh, _Float16* __restrict__ kh, _Float16* __restrict__ vth)
{
    const int proj = blockIdx.z;
    const float* __restrict__ X  = (proj == 0) ? Qx : (proj == 1) ? Kx : Vx;
    const float* __restrict__ W  = (proj == 0) ? WQ : (proj == 1) ? WK : WV;
    const float* __restrict__ bb = (proj == 0) ? bQ : (proj == 1) ? bK : bV;

    const int row0 = blockIdx.x * 64;     // global row (b*512+s), no b-crossing
    const int t = threadIdx.x;
    const int w = t >> 6, l = t & 63;
    const int lm16 = l & 15, lg = l >> 4;

    // lane base pointers; frag (mi|ni, slice s) at base + f*4096 + s*16
    const float* xb0 = X + (size_t)(row0 + lm16) * 256 + lg * 4;
    const float* wb0 = W + (size_t)(w * 64 + lm16) * 256 + lg * 4;

    f32x4 acc[4][4];
#pragma unroll
    for (int mi = 0; mi < 4; mi++)
#pragma unroll
        for (int ni = 0; ni < 4; ni++) acc[mi][ni] = (f32x4){0.f, 0.f, 0.f, 0.f};

    float4 xA[4], wA[4], xB[4], wB[4];    // ping-pong slice buffers

    // prologue: slice 0 -> A
#pragma unroll
    for (int f = 0; f < 4; f++) {
        xA[f] = *(const float4*)(xb0 + f * 4096);
        wA[f] = *(const float4*)(wb0 + f * 4096);
    }

#pragma unroll 1
    for (int sp = 0; sp < 8; sp++) {      // slices 2sp (A) and 2sp+1 (B)
        const int offB = (2 * sp + 1) * 16;
#pragma unroll
        for (int f = 0; f < 4; f++) {     // prefetch B
            xB[f] = *(const float4*)(xb0 + f * 4096 + offB);
            wB[f] = *(const float4*)(wb0 + f * 4096 + offB);
        }
        mfma_slice(proj, xA, wA, acc);    // compute slice 2sp
        if (sp < 7) {
            const int offA = (2 * sp + 2) * 16;
#pragma unroll
            for (int f = 0; f < 4; f++) { // prefetch next A
                xA[f] = *(const float4*)(xb0 + f * 4096 + offA);
                wA[f] = *(const float4*)(wb0 + f * 4096 + offA);
            }
        }
        mfma_slice(proj, xB, wB, acc);    // compute slice 2sp+1
    }

    const int bq = row0 >> 9;
    const int sbase = row0 & 511;

    if (proj < 2) {
        // D row = W col (lane: col0+r, 4 consecutive d), D col = X row (lm16)
        const float scl = (proj == 0) ? 0.25f * LOG2E : 1.0f;
        _Float16* __restrict__ outp = (proj == 0) ? qh : kh;
#pragma unroll
        for (int mi = 0; mi < 4; mi++) {
            const int s = sbase + mi * 16 + lm16;
#pragma unroll
            for (int ni = 0; ni < 4; ni++) {
                const int col0 = w * 64 + ni * 16 + lg * 4;   // head-aligned
                const int h = col0 >> 4, d0 = col0 & 15;
                const float4 bv = *(const float4*)&bb[col0];
                _Float16 tmp[4];
                tmp[0] = (_Float16)((acc[mi][ni][0] + bv.x) * scl);
                tmp[1] = (_Float16)((acc[mi][ni][1] + bv.y) * scl);
                tmp[2] = (_Float16)((acc[mi][ni][2] + bv.z) * scl);
                tmp[3] = (_Float16)((acc[mi][ni][3] + bv.w) * scl);
                *(f16x4*)&outp[(((size_t)bq * 16 + h) * 512 + s) * 16 + d0] =
                    *(const f16x4*)tmp;
            }
        }
    } else {
        // D row = X row (lane: s0+r, 4 consecutive s), D col = W col (lm16)
#pragma unroll
        for (int mi = 0; mi < 4; mi++) {
            const int s0 = sbase + mi * 16 + lg * 4;
#pragma unroll
            for (int ni = 0; ni < 4; ni++) {
                const int col = w * 64 + ni * 16 + lm16;
                const int h = col >> 4, d = col & 15;
                const float bc = bb[col];
                _Float16 tmp[4];
#pragma unroll
                for (int r = 0; r < 4; r++)
                    tmp[r] = (_Float16)(acc[mi][ni][r] + bc);
                *(f16x4*)&vth[(((size_t)bq * 16 + h) * 16 + d) * 512 + s0] =
                    *(const f16x4*)tmp;
            }
        }
    }
}

// ---------------------------------------------------------------------------
// MFMA attention (unchanged, verified). Block = (bh, half): 4 waves, each
// owns 64 q-rows. Per j-tile: S^T = mfma(A=K, B=Q, C=log2(mask)) -> exp2 ->
// P in-register (== PV A-frag layout) -> ctx += mfma(P, V).
// ---------------------------------------------------------------------------
__global__ __launch_bounds__(256, 4) void attn_mfma(
    const _Float16* __restrict__ qh, const _Float16* __restrict__ kh,
    const _Float16* __restrict__ vth, const float* __restrict__ mask,
    float* __restrict__ out)
{
    const int blk  = blockIdx.x;     // bh*2 + half
    const int bh   = blk >> 1;
    const int half = blk & 1;
    const int b = bh >> 4, h = bh & 15;

    __shared__ _Float16 ks[512 * 16];   // [s][16] 16 KB
    __shared__ _Float16 vt[16 * 528];   // [d][528] padded, 16.5 KB
    __shared__ float    lm[512];        // log2(mask)
    __shared__ float    sums[256];      // [wave][64 rowsums]

    const int t = threadIdx.x;
    const int w = t >> 6, l = t & 63;
    const int lm16 = l & 15, lg = l >> 4;

    {   // stage K (linear)
        const float4* src = (const float4*)(kh + (size_t)bh * 8192);
        float4* dst = (float4*)ks;
#pragma unroll
        for (int i = 0; i < 4; i++) dst[t + i * 256] = src[t + i * 256];
    }
    {   // stage V^T with row pad 512->528
        const _Float16* src = vth + (size_t)bh * 8192;
#pragma unroll
        for (int i = 0; i < 4; i++) {
            int f = t + i * 256;           // 1024 chunks of 8 f16
            int d = f >> 6, c = f & 63;
            *(float4*)&vt[d * 528 + c * 8] = *(const float4*)&src[d * 512 + c * 8];
        }
    }
    {   // mask -> log2 (log2(0) = -inf -> exp2 = 0, exact)
#pragma unroll
        for (int i = 0; i < 2; i++) {
            int j = t + i * 256;
            lm[j] = __builtin_amdgcn_logf(mask[b * 512 + j]);
        }
    }

    // preload Q B-fragments: lane supplies Q[m0 + (l&15)][(l>>4)*4 + i]
    f16x4 qf[4];
    {
        const _Float16* qb = qh + (size_t)bh * 8192;
#pragma unroll
        for (int mt = 0; mt < 4; mt++) {
            int m = half * 256 + w * 64 + mt * 16 + lm16;
            qf[mt] = *(const f16x4*)&qb[m * 16 + lg * 4];
        }
    }

    f32x4 acc[4];
    float rs[4];
#pragma unroll
    for (int mt = 0; mt < 4; mt++) {
        acc[mt] = (f32x4){0.f, 0.f, 0.f, 0.f};
        rs[mt] = 0.f;
    }

    __syncthreads();

    for (int jt = 0; jt < 32; jt++) {
        const int j0 = jt << 4;
        f16x4 ka = *(const f16x4*)&ks[(j0 + lm16) * 16 + lg * 4];
        f16x4 vb = *(const f16x4*)&vt[lm16 * 528 + j0 + lg * 4];
        f32x4 lmv = *(const f32x4*)&lm[j0 + lg * 4];
#pragma unroll
        for (int mt = 0; mt < 4; mt++) {
            f32x4 s4 = __builtin_amdgcn_mfma_f32_16x16x16f16(ka, qf[mt], lmv, 0, 0, 0);
            float e0 = __builtin_amdgcn_exp2f(s4[0]);
            float e1 = __builtin_amdgcn_exp2f(s4[1]);
            float e2 = __builtin_amdgcn_exp2f(s4[2]);
            float e3 = __builtin_amdgcn_exp2f(s4[3]);
            rs[mt] += (e0 + e1) + (e2 + e3);
            f16x4 pa;
            pa[0] = (_Float16)e0; pa[1] = (_Float16)e1;
            pa[2] = (_Float16)e2; pa[3] = (_Float16)e3;
            acc[mt] = __builtin_amdgcn_mfma_f32_16x16x16f16(pa, vb, acc[mt], 0, 0, 0);
        }
    }

    // rowsum: lanes {m, m+16, m+32, m+48} hold partials for col m = l&15
#pragma unroll
    for (int mt = 0; mt < 4; mt++) {
        float r = rs[mt];
        r += __shfl_xor(r, 16);
        r += __shfl_xor(r, 32);
        if (l < 16) sums[w * 64 + mt * 16 + l] = r;
    }
    __syncthreads();

#pragma unroll
    for (int mt = 0; mt < 4; mt++) {
        f32x4 sv = *(const f32x4*)&sums[w * 64 + mt * 16 + lg * 4];
        int m = half * 256 + w * 64 + mt * 16 + lg * 4;
        float* o = out + ((size_t)(b * 512 + m) * 256) + h * 16 + lm16;
        o[0]   = acc[mt][0] / (sv[0] + 1e-8f);
        o[256] = acc[mt][1] / (sv[1] + 1e-8f);
        o[512] = acc[mt][2] / (sv[2] + 1e-8f);
        o[768] = acc[mt][3] / (sv[3] + 1e-8f);
    }
}

extern "C" void kernel_launch(void* const* d_in, const int* in_sizes, int n_in,
                              void* d_out, int out_size, void* d_ws, size_t ws_size,
                              hipStream_t stream) {
    const float* Q    = (const float*)d_in[0];
    const float* K    = (const float*)d_in[1];
    const float* V    = (const float*)d_in[2];
    const float* mask = (const float*)d_in[3];
    const float* W_Q  = (const float*)d_in[4];
    const float* b_Q  = (const float*)d_in[5];
    const float* W_K  = (const float*)d_in[6];
    const float* b_K  = (const float*)d_in[7];
    const float* W_V  = (const float*)d_in[8];
    const float* b_V  = (const float*)d_in[9];
    float* out = (float*)d_out;

    _Float16* qh  = (_Float16*)d_ws;            // [bh][s][16], pre-scaled
    _Float16* kh  = qh + PROJ_ELEMS;            // [bh][s][16]
    _Float16* vth = kh + PROJ_ELEMS;            // [bh][d][s]

    proj_mfma<<<dim3(256, 1, 3), 256, 0, stream>>>(
        Q, K, V, W_Q, b_Q, W_K, b_K, W_V, b_V, qh, kh, vth);

    attn_mfma<<<dim3(32 * 16 * 2), 256, 0, stream>>>(qh, kh, vth, mask, out);
}

// Round 15
// 152.910 us; speedup vs baseline: 2.3059x; 1.1006x over previous
//
#include <hip/hip_runtime.h>
#include <hip/hip_bf16.h>

// B=32, S=512, D_MODEL=256, H=16, D_K=D_V=16
// proj_mfma v5: m97-style GEMM. 128x128 tile, BK=32, fp32 LDS tiles staged
// via __builtin_amdgcn_global_load_lds (no VGPR destinations -> compiler
// cannot serialize the staging; rounds 8/10/12 all showed VGPR=92 serial
// loads). XOR-swizzle (row&7)<<4 applied to BOTH the global source address
// and the LDS read address (LDS itself linear, as the DMA requires).
// attn_mfma: unchanged (verified rounds 6/8/10/12).

#define PROJ_ELEMS (32 * 16 * 512 * 16) // 4,194,304 elems per projected tensor
#define LOG2E 1.44269504088896f

typedef _Float16 f16x4 __attribute__((ext_vector_type(4)));
typedef float    f32x4 __attribute__((ext_vector_type(4)));

static __device__ __forceinline__ f16x4 cvt4(float4 v) {
    f16x4 r;
    r[0] = (_Float16)v.x; r[1] = (_Float16)v.y;
    r[2] = (_Float16)v.z; r[3] = (_Float16)v.w;
    return r;
}

static __device__ __forceinline__ void gl_lds16(const void* g, void* l) {
    __builtin_amdgcn_global_load_lds(
        (const __attribute__((address_space(1))) unsigned int*)g,
        (__attribute__((address_space(3))) unsigned int*)l,
        16, 0, 0);
}

// ---------------------------------------------------------------------------
// Block = 128 rows x 128 cols (grid y = col-block of 2), BK=32, 4 waves,
// wave w owns quadrant rows (w&1)*64, cols (w>>1)*64 (4x4 16x16 tiles).
// LDS per buffer: X[128][32] fp32 16KB + W[128][32] fp32 16KB; 2 buffers.
// Swizzle: byte-in-row ^= (row&7)<<4 on global src AND on ds_read addr.
// mfma_f32_16x16x16f16 lane algebra (verified r6-r12): D row = A-operand row
// (lg*4+reg), D col = B-operand row (lm16); frag = op[lm16-row][lg*4+i of k].
// Q/K: A=W, B=X -> lane packs 4 consecutive d.  V: A=X, B=W -> 4 consec. s.
// ---------------------------------------------------------------------------
__global__ __launch_bounds__(256, 2) void proj_mfma(
    const float* __restrict__ Qx, const float* __restrict__ Kx, const float* __restrict__ Vx,
    const float* __restrict__ WQ, const float* __restrict__ bQ,
    const float* __restrict__ WK, const float* __restrict__ bK,
    const float* __restrict__ WV, const float* __restrict__ bV,
    _Float16* __restrict__ qh, _Float16* __restrict__ kh, _Float16* __restrict__ vth)
{
    const int proj = blockIdx.z;
    const float* __restrict__ X  = (proj == 0) ? Qx : (proj == 1) ? Kx : Vx;
    const float* __restrict__ W  = (proj == 0) ? WQ : (proj == 1) ? WK : WV;
    const float* __restrict__ bb = (proj == 0) ? bQ : (proj == 1) ? bK : bV;

    const int row0 = blockIdx.x * 128;    // global row (b*512+s)
    const int colb = blockIdx.y;          // col-block: cols colb*128 + 0..127
    const int t = threadIdx.x;
    const int w = t >> 6, l = t & 63;
    const int lm16 = l & 15, lg = l >> 4;

    __shared__ float4 lds4[4096];         // 64KB: [buf][X 16KB | W 16KB]
    char* ldsc = (char*)lds4;

    // staging source: lane covers row rw (j adds 8 rows/issue), 16B at swizzled
    // in-row offset. Row stride in global = 256 fp32 = 1024B.
    const int rw = w * 32 + (l >> 3);
    const int swzs = ((l & 7) * 16) ^ ((rw & 7) << 4);
    const char* gx = (const char*)X + (size_t)(row0 + rw) * 1024 + swzs;
    const char* gw = (const char*)W + (size_t)(colb * 128 + rw) * 1024 + swzs;

#define STAGE(buf, ks) do {                                                  \
    char* bx_ = ldsc + (buf) * 32768;                                        \
    char* bw_ = bx_ + 16384;                                                 \
    _Pragma("unroll")                                                        \
    for (int j = 0; j < 4; j++) {                                            \
        gl_lds16(gx + (ks) * 128 + j * 8192, bx_ + w * 4096 + j * 1024);     \
        gl_lds16(gw + (ks) * 128 + j * 8192, bw_ + w * 4096 + j * 1024);     \
    } } while (0)

    f32x4 acc[4][4];
#pragma unroll
    for (int mi = 0; mi < 4; mi++)
#pragma unroll
        for (int ni = 0; ni < 4; ni++) acc[mi][ni] = (f32x4){0.f, 0.f, 0.f, 0.f};

    const int fswz = (lm16 & 7) << 4;     // read-side swizzle (row&7 == lm16&7)

    STAGE(0, 0);
    __syncthreads();

#pragma unroll 1
    for (int ks = 0; ks < 8; ks++) {
        if (ks < 7) STAGE((ks + 1) & 1, ks + 1);
        const char* xt = ldsc + (ks & 1) * 32768;
        const char* wt = xt + 16384;
#pragma unroll
        for (int s = 0; s < 2; s++) {     // two 16-wide k slices in BK=32
            const int inrow = (s * 64 + lg * 16) ^ fswz;
            f16x4 xf[4], wf[4];
#pragma unroll
            for (int mi = 0; mi < 4; mi++) {
                const int row = (w & 1) * 64 + mi * 16 + lm16;
                xf[mi] = cvt4(*(const float4*)(xt + row * 128 + inrow));
            }
#pragma unroll
            for (int ni = 0; ni < 4; ni++) {
                const int row = (w >> 1) * 64 + ni * 16 + lm16;
                wf[ni] = cvt4(*(const float4*)(wt + row * 128 + inrow));
            }
            if (proj < 2) {
#pragma unroll
                for (int mi = 0; mi < 4; mi++)
#pragma unroll
                    for (int ni = 0; ni < 4; ni++)
                        acc[mi][ni] = __builtin_amdgcn_mfma_f32_16x16x16f16(
                            wf[ni], xf[mi], acc[mi][ni], 0, 0, 0);
            } else {
#pragma unroll
                for (int mi = 0; mi < 4; mi++)
#pragma unroll
                    for (int ni = 0; ni < 4; ni++)
                        acc[mi][ni] = __builtin_amdgcn_mfma_f32_16x16x16f16(
                            xf[mi], wf[ni], acc[mi][ni], 0, 0, 0);
            }
        }
        __syncthreads();
    }
#undef STAGE

    const int bq = row0 >> 9;
    const int sbase = row0 & 511;

    if (proj < 2) {
        // D row = W col (lane: col0+r, 4 consecutive d), D col = X row (lm16)
        const float scl = (proj == 0) ? 0.25f * LOG2E : 1.0f;
        _Float16* __restrict__ outp = (proj == 0) ? qh : kh;
#pragma unroll
        for (int mi = 0; mi < 4; mi++) {
            const int s = sbase + (w & 1) * 64 + mi * 16 + lm16;
#pragma unroll
            for (int ni = 0; ni < 4; ni++) {
                const int col0 = colb * 128 + (w >> 1) * 64 + ni * 16 + lg * 4;
                const int h = col0 >> 4, d0 = col0 & 15;
                const float4 bv = *(const float4*)&bb[col0];
                _Float16 tmp[4];
                tmp[0] = (_Float16)((acc[mi][ni][0] + bv.x) * scl);
                tmp[1] = (_Float16)((acc[mi][ni][1] + bv.y) * scl);
                tmp[2] = (_Float16)((acc[mi][ni][2] + bv.z) * scl);
                tmp[3] = (_Float16)((acc[mi][ni][3] + bv.w) * scl);
                *(f16x4*)&outp[(((size_t)bq * 16 + h) * 512 + s) * 16 + d0] =
                    *(const f16x4*)tmp;
            }
        }
    } else {
        // D row = X row (lane: s0+r, 4 consecutive s), D col = W col (lm16)
#pragma unroll
        for (int mi = 0; mi < 4; mi++) {
            const int s0 = sbase + (w & 1) * 64 + mi * 16 + lg * 4;
#pragma unroll
            for (int ni = 0; ni < 4; ni++) {
                const int col = colb * 128 + (w >> 1) * 64 + ni * 16 + lm16;
                const int h = col >> 4, d = col & 15;
                const float bc = bb[col];
                _Float16 tmp[4];
#pragma unroll
                for (int r = 0; r < 4; r++)
                    tmp[r] = (_Float16)(acc[mi][ni][r] + bc);
                *(f16x4*)&vth[(((size_t)bq * 16 + h) * 16 + d) * 512 + s0] =
                    *(const f16x4*)tmp;
            }
        }
    }
}

// ---------------------------------------------------------------------------
// MFMA attention (unchanged, verified). Block = (bh, half): 4 waves, each
// owns 64 q-rows. Per j-tile: S^T = mfma(A=K, B=Q, C=log2(mask)) -> exp2 ->
// P in-register (== PV A-frag layout) -> ctx += mfma(P, V).
// ---------------------------------------------------------------------------
__global__ __launch_bounds__(256, 4) void attn_mfma(
    const _Float16* __restrict__ qh, const _Float16* __restrict__ kh,
    const _Float16* __restrict__ vth, const float* __restrict__ mask,
    float* __restrict__ out)
{
    const int blk  = blockIdx.x;     // bh*2 + half
    const int bh   = blk >> 1;
    const int half = blk & 1;
    const int b = bh >> 4, h = bh & 15;

    __shared__ _Float16 ks[512 * 16];   // [s][16] 16 KB
    __shared__ _Float16 vt[16 * 528];   // [d][528] padded, 16.5 KB
    __shared__ float    lm[512];        // log2(mask)
    __shared__ float    sums[256];      // [wave][64 rowsums]

    const int t = threadIdx.x;
    const int w = t >> 6, l = t & 63;
    const int lm16 = l & 15, lg = l >> 4;

    {   // stage K (linear)
        const float4* src = (const float4*)(kh + (size_t)bh * 8192);
        float4* dst = (float4*)ks;
#pragma unroll
        for (int i = 0; i < 4; i++) dst[t + i * 256] = src[t + i * 256];
    }
    {   // stage V^T with row pad 512->528
        const _Float16* src = vth + (size_t)bh * 8192;
#pragma unroll
        for (int i = 0; i < 4; i++) {
            int f = t + i * 256;           // 1024 chunks of 8 f16
            int d = f >> 6, c = f & 63;
            *(float4*)&vt[d * 528 + c * 8] = *(const float4*)&src[d * 512 + c * 8];
        }
    }
    {   // mask -> log2 (log2(0) = -inf -> exp2 = 0, exact)
#pragma unroll
        for (int i = 0; i < 2; i++) {
            int j = t + i * 256;
            lm[j] = __builtin_amdgcn_logf(mask[b * 512 + j]);
        }
    }

    // preload Q B-fragments: lane supplies Q[m0 + (l&15)][(l>>4)*4 + i]
    f16x4 qf[4];
    {
        const _Float16* qb = qh + (size_t)bh * 8192;
#pragma unroll
        for (int mt = 0; mt < 4; mt++) {
            int m = half * 256 + w * 64 + mt * 16 + lm16;
            qf[mt] = *(const f16x4*)&qb[m * 16 + lg * 4];
        }
    }

    f32x4 acc[4];
    float rs[4];
#pragma unroll
    for (int mt = 0; mt < 4; mt++) {
        acc[mt] = (f32x4){0.f, 0.f, 0.f, 0.f};
        rs[mt] = 0.f;
    }

    __syncthreads();

    for (int jt = 0; jt < 32; jt++) {
        const int j0 = jt << 4;
        f16x4 ka = *(const f16x4*)&ks[(j0 + lm16) * 16 + lg * 4];
        f16x4 vb = *(const f16x4*)&vt[lm16 * 528 + j0 + lg * 4];
        f32x4 lmv = *(const f32x4*)&lm[j0 + lg * 4];
#pragma unroll
        for (int mt = 0; mt < 4; mt++) {
            f32x4 s4 = __builtin_amdgcn_mfma_f32_16x16x16f16(ka, qf[mt], lmv, 0, 0, 0);
            float e0 = __builtin_amdgcn_exp2f(s4[0]);
            float e1 = __builtin_amdgcn_exp2f(s4[1]);
            float e2 = __builtin_amdgcn_exp2f(s4[2]);
            float e3 = __builtin_amdgcn_exp2f(s4[3]);
            rs[mt] += (e0 + e1) + (e2 + e3);
            f16x4 pa;
            pa[0] = (_Float16)e0; pa[1] = (_Float16)e1;
            pa[2] = (_Float16)e2; pa[3] = (_Float16)e3;
            acc[mt] = __builtin_amdgcn_mfma_f32_16x16x16f16(pa, vb, acc[mt], 0, 0, 0);
        }
    }

    // rowsum: lanes {m, m+16, m+32, m+48} hold partials for col m = l&15
#pragma unroll
    for (int mt = 0; mt < 4; mt++) {
        float r = rs[mt];
        r += __shfl_xor(r, 16);
        r += __shfl_xor(r, 32);
        if (l < 16) sums[w * 64 + mt * 16 + l] = r;
    }
    __syncthreads();

#pragma unroll
    for (int mt = 0; mt < 4; mt++) {
        f32x4 sv = *(const f32x4*)&sums[w * 64 + mt * 16 + lg * 4];
        int m = half * 256 + w * 64 + mt * 16 + lg * 4;
        float* o = out + ((size_t)(b * 512 + m) * 256) + h * 16 + lm16;
        o[0]   = acc[mt][0] / (sv[0] + 1e-8f);
        o[256] = acc[mt][1] / (sv[1] + 1e-8f);
        o[512] = acc[mt][2] / (sv[2] + 1e-8f);
        o[768] = acc[mt][3] / (sv[3] + 1e-8f);
    }
}

extern "C" void kernel_launch(void* const* d_in, const int* in_sizes, int n_in,
                              void* d_out, int out_size, void* d_ws, size_t ws_size,
                              hipStream_t stream) {
    const float* Q    = (const float*)d_in[0];
    const float* K    = (const float*)d_in[1];
    const float* V    = (const float*)d_in[2];
    const float* mask = (const float*)d_in[3];
    const float* W_Q  = (const float*)d_in[4];
    const float* b_Q  = (const float*)d_in[5];
    const float* W_K  = (const float*)d_in[6];
    const float* b_K  = (const float*)d_in[7];
    const float* W_V  = (const float*)d_in[8];
    const float* b_V  = (const float*)d_in[9];
    float* out = (float*)d_out;

    _Float16* qh  = (_Float16*)d_ws;            // [bh][s][16], pre-scaled
    _Float16* kh  = qh + PROJ_ELEMS;            // [bh][s][16]
    _Float16* vth = kh + PROJ_ELEMS;            // [bh][d][s]

    proj_mfma<<<dim3(128, 2, 3), 256, 0, stream>>>(
        Q, K, V, W_Q, b_Q, W_K, b_K, W_V, b_V, qh, kh, vth);

    attn_mfma<<<dim3(32 * 16 * 2), 256, 0, stream>>>(qh, kh, vth, mask, out);
}